// Round 11
// baseline (4347.622 us; speedup 1.0000x reference)
//
#include <hip/hip_runtime.h>
#include <math.h>

#define BB 8
#define LL 512
#define DD 256
#define NG4 1024
#define WGB 32     // WGs per batch
#define WR 16      // mem rows per WG
#define WU 8       // units per WG
#define MLD 264    // padded leading dim for mems tile

typedef __attribute__((ext_vector_type(4))) float f32x4;
typedef __attribute__((ext_vector_type(2))) unsigned u32x2;
typedef __attribute__((ext_vector_type(4))) unsigned u32x4;

// ---- workspace layout (float offsets) ----
static const size_t OFF_XW    = 0;
static const size_t OFF_F     = OFF_XW + (size_t)BB*LL*NG4;     // F = Wc_top @ Ww   (256x1024)
static const size_t OFF_BMW   = OFF_F + (size_t)DD*NG4;         // Bm = Wc_bot @ Ww  (256x1024)
static const size_t OFF_B2    = OFF_BMW + (size_t)DD*NG4;       // b2 = b_c@Ww + b_w (1024)
static const size_t OFF_HRT   = OFF_B2 + NG4;                   // [2][B][256] {val,tag}
static const size_t OFF_HWT   = OFF_HRT + (size_t)2*BB*DD*2;    // [B][256] {val,tag}
static const size_t OFF_RHOT  = OFF_HWT + (size_t)BB*DD*2;      // [B][32] {val,tag}
static const size_t OFF_CH2   = OFF_RHOT + (size_t)BB*WGB*2;    // [B][32] {psum, 0}
static const size_t OFF_FLG   = OFF_CH2 + (size_t)BB*WGB*2;     // [B][32] {pmax, tag}
static const size_t OFF_PM    = OFF_FLG + (size_t)BB*WGB*2;     // [B][32][256] plain
static const size_t TOTAL_WS  = OFF_PM + (size_t)BB*WGB*DD;     // floats

__device__ __forceinline__ float hsig(float x) {
    return fminf(fmaxf(0.2f*x + 0.5f, 0.0f), 1.0f);
}

// coherent (MALL, sc0 sc1) scalar store
__device__ __forceinline__ void st_coh(float* p, float v) {
    __hip_atomic_store(p, v, __ATOMIC_RELAXED, __HIP_MEMORY_SCOPE_AGENT);
}
// tagged 8B pair {f32 value, u32 epoch} in one coherent store
__device__ __forceinline__ void st_pair(unsigned* p, float v, unsigned tag) {
    u32x2 d; d[0] = __float_as_uint(v); d[1] = tag;
    asm volatile("global_store_dwordx2 %0, %1, off sc0 sc1" :: "v"(p), "v"(d) : "memory");
}
__device__ __forceinline__ u32x2 ld_pair(const unsigned* p) {
    u32x2 r;
    asm volatile("global_load_dwordx2 %0, %1, off sc0 sc1\n\ts_waitcnt vmcnt(0)"
                 : "=&v"(r) : "v"(p) : "memory");
    return r;
}
// fallback slow poll (rare-stale path)
__device__ __forceinline__ float poll_pair(const unsigned* p, unsigned tag) {
    for (;;) {
        u32x2 r = ld_pair(p);
        if (r[1] >= tag) return __uint_as_float(r[0]);
    }
}

// ---- simple fp32 tiled GEMM ----
template<int TM, int TN, int TK>
__global__ void __launch_bounds__(256) gemm_nn(
    const float* __restrict__ A, int lda,
    const float* __restrict__ Bmat, int ldb,
    const float* __restrict__ bias,
    float* __restrict__ C, int ldc,
    int M, int N, int K)
{
    __shared__ float As[TK][TM];
    __shared__ float Bs[TK][TN];
    const int m0 = blockIdx.y * TM, n0 = blockIdx.x * TN;
    const int tid = threadIdx.x;
    const int tx = tid % (TN/4);
    const int ty = tid / (TN/4);
    float acc[4][4] = {};
    for (int k0 = 0; k0 < K; k0 += TK) {
        {
            const int e = tid*4;
            const int m = e / TK, k = e % TK;
            const float4 v = *reinterpret_cast<const float4*>(&A[(size_t)(m0+m)*lda + k0 + k]);
            As[k+0][m] = v.x; As[k+1][m] = v.y; As[k+2][m] = v.z; As[k+3][m] = v.w;
        }
        {
            const int e = tid*4;
            const int k = e / TN, n = e % TN;
            const float4 v = *reinterpret_cast<const float4*>(&Bmat[(size_t)(k0+k)*ldb + n0 + n]);
            Bs[k][n+0] = v.x; Bs[k][n+1] = v.y; Bs[k][n+2] = v.z; Bs[k][n+3] = v.w;
        }
        __syncthreads();
        #pragma unroll
        for (int kk = 0; kk < TK; ++kk) {
            float a[4], bv[4];
            #pragma unroll
            for (int i = 0; i < 4; ++i) a[i] = As[kk][ty*4+i];
            #pragma unroll
            for (int j = 0; j < 4; ++j) bv[j] = Bs[kk][tx*4+j];
            #pragma unroll
            for (int i = 0; i < 4; ++i)
                #pragma unroll
                for (int j = 0; j < 4; ++j) acc[i][j] += a[i]*bv[j];
        }
        __syncthreads();
    }
    #pragma unroll
    for (int i = 0; i < 4; ++i) {
        const int m = m0 + ty*4 + i;
        #pragma unroll
        for (int j = 0; j < 4; ++j) {
            const int n = n0 + tx*4 + j;
            C[(size_t)m*ldc + n] = acc[i][j] + (bias ? bias[n] : 0.0f);
        }
    }
}

// b2[n] = b_w[n] + sum_k b_c[k]*W_w[k][n]
__global__ void __launch_bounds__(256) b2_kernel(
    const float* __restrict__ bc, const float* __restrict__ Ww,
    const float* __restrict__ bw, float* __restrict__ B2)
{
    const int n = blockIdx.x*256 + threadIdx.x;
    float a = bw[n];
    for (int k = 0; k < DD; ++k) a += bc[k]*Ww[(size_t)k*NG4 + n];
    B2[n] = a;
}

// ---- fused reader+writer persistent kernel ----
// r8 dataflow (validated), rescheduled:
//  - A1: ONE asm block early-issues hw+hr pair loads, then runs the rho poll
//    loop (its vmcnt(0) retires them). Consume-time = tag check, not poll.
//  - A2: pm + CH2{psum} published; A3 compute runs; vmcnt(0) then is free;
//    lane0 publishes FLG{pmax,tag} (drain-certifies pm+CH2).
//  - B1: poll cheap 8B FLG (u64 compare: tag>=s <=> pair >= s<<32), then one
//    batched load {CH2 + 8x dwordx4 pm}.
// Overrun-safety: producers of epoch e+1 are gated behind consuming epoch e
// from ALL peers, so during any poll/read window tags cannot pass the target.
__global__ void __launch_bounds__(256) fused_kernel(
    const float* __restrict__ XW, const float* __restrict__ Fw,
    const float* __restrict__ Bm, const float* __restrict__ B2,
    const float* __restrict__ Ur, const float* __restrict__ Uw,
    const float* __restrict__ x,
    unsigned* __restrict__ HRT, unsigned* __restrict__ HWT,
    unsigned* __restrict__ RHOT, unsigned* __restrict__ CH2,
    unsigned* __restrict__ FLG, float* __restrict__ PMf,
    float* __restrict__ out)
{
    extern __shared__ float sm[];
    float* Urs  = sm;              // [256][32]
    float* Uws  = Urs + 8192;      // [256][32]
    float* Fs   = Uws + 8192;      // [256][32]
    float* Bms  = Fs + 8192;       // [256][32]
    float* mems = Bms + 8192;      // [16][MLD]
    float* hr2  = mems + WR*MLD;   // [2][256] h_r parity slots
    float* hw   = hr2 + 512;       // 256
    float* ms   = hw + 256;        // 256
    float* zredR= ms + 256;        // 256
    float* zredW= zredR + 256;     // 256
    float* red4 = zredW + 256;     // [4][256]
    float* xws  = red4 + 1024;     // 32
    float* b2s  = xws + 32;        // 32
    float* zrs  = b2s + 32;        // 32
    float* zws  = zrs + 32;        // 32
    float* fwS  = zws + 32;        // 32
    float* d1   = fwS + 32;        // 16
    float* zp   = d1 + 16;         // 16
    float* esx  = zp + 16;         // 16
    float* wv   = esx + 16;        // 16
    float* cr   = wv + 16;         // 8
    float* cw   = cr + 8;          // 8
    float* misc = cw + 8;          // [0]=zp scale, [1]=invS, [2]=beta

    const int b   = (int)blockIdx.x & 7;
    const int wg  = (int)blockIdx.x >> 3;   // 0..31
    const int tid = threadIdx.x;
    const int R0  = wg*WR;
    const int U0  = wg*WU;
    const int gc32 = (tid>>3)*DD + U0 + (tid&7);   // global col for lane<32

    // --- init: weight slices ---
    for (int it = 0; it < 32; ++it) {
        const int e = it*256 + tid;
        const int k = e >> 5, cl = e & 31;
        const int gc = (cl>>3)*DD + U0 + (cl&7);
        Urs[k*32+cl] = Ur[(size_t)k*NG4 + gc];
        Uws[k*32+cl] = Uw[(size_t)k*NG4 + gc];
        Fs [k*32+cl] = Fw[(size_t)k*NG4 + gc];
        Bms[k*32+cl] = Bm[(size_t)k*NG4 + gc];
    }
    if (tid < 32) b2s[tid] = B2[gc32];
    for (int r = 0; r < WR; ++r)
        mems[r*MLD + tid] = x[((size_t)b*LL + R0 + r)*DD + tid];
    // prologue: full h_r[0] computed locally (h=0 -> z = XW row 0)
    {
        const size_t base = (size_t)b*LL*NG4;
        const float zi = XW[base + tid];
        const float zg = XW[base + 512 + tid];
        const float zo = XW[base + 768 + tid];
        const float c0 = hsig(zi)*tanhf(zg);
        hr2[tid] = hsig(zo)*tanhf(c0);
        hr2[256 + tid] = 0.f;
        if (tid >= U0 && tid < U0+WU) cr[tid-U0] = c0;
    }
    if (tid < 16) { zp[tid] = 0.f; d1[tid] = 0.f; esx[tid] = 0.f; }
    if (tid < 8)  cw[tid] = 0.f;
    if (tid < 4)  misc[tid] = 0.f;
    __syncthreads();

    for (int s = 0; s <= LL; ++s) {
        const bool doW = (s >= 1);
        const unsigned us = (unsigned)s;
        float* hrN_s = hr2 + (s&1)*256;        // h_r[s]
        float* hrO_s = hr2 + ((s+1)&1)*256;    // h_r[s-1] = o_tau

        // ================= PHASE A1 =================
        // one asm block: early-issue hw+hr pair loads, then rho poll loop
        const unsigned* phw = HWT + 2*((size_t)b*DD + tid);
        const unsigned* phr = HRT + 2*((((size_t)(s&1))*BB + b)*DD + tid);
        const unsigned* prh = RHOT + 2*(b*WGB + (tid & 31));
        const unsigned long long trho = (s >= 2) ? ((unsigned long long)(s-1) << 32) : 0ull;
        unsigned long long hwp, hrp, rrp;
        asm volatile(
            "global_load_dwordx2 %[hw], %[phw], off sc0 sc1\n\t"
            "global_load_dwordx2 %[hr], %[phr], off sc0 sc1\n\t"
            "1:\n\t"
            "global_load_dwordx2 %[rr], %[prh], off sc0 sc1\n\t"
            "s_waitcnt vmcnt(0)\n\t"
            "v_cmp_gt_u64 vcc, %[tr], %[rr]\n\t"
            "s_cbranch_vccnz 1b"
            : [hw]"=&v"(hwp), [hr]"=&v"(hrp), [rr]"=&v"(rrp)
            : [phw]"v"(phw), [phr]"v"(phr), [prh]"v"(prh), [tr]"s"(trho)
            : "vcc", "memory");

        const float rho_r = (s >= 2) ? __uint_as_float((unsigned)rrp) : 0.f;
        float hw_r = 0.f;
        if (s >= 2) {
            hw_r = ((unsigned)(hwp >> 32) >= us - 1u)
                 ? __uint_as_float((unsigned)hwp) : poll_pair(phw, us - 1u);
        }
        if (s >= 1 && s <= LL-1) {
            const float hrN_r = ((unsigned)(hrp >> 32) >= us)
                 ? __uint_as_float((unsigned)hrp) : poll_pair(phr, us);
            hrN_s[tid] = hrN_r;
        }
        hw[tid] = hw_r;
        if (s <= LL-2 && tid < 32)
            xws[tid] = XW[((size_t)b*LL + s + 1)*NG4 + gc32];

        // d2 from rho partials + local softmax (wave 0)
        float ck_m = 0.f;
        if (tid < 32) {
            float d2 = rho_r;
            #pragma unroll
            for (int off = 16; off; off >>= 1) d2 += __shfl_xor(d2, off, 32);
            if (doW && tid < 16) {
                const float zpv = zp[tid];
                const float sc  = (1.f - zpv)*d1[tid] + zpv*d2;
                float m = sc;
                #pragma unroll
                for (int off = 8; off; off >>= 1) m = fmaxf(m, __shfl_xor(m, off, 16));
                const float e = __expf(sc - m);
                esx[tid] = e;
                wv[tid]  = e*(1.f - zpv);
                float sum = e, bp = e*zpv;
                #pragma unroll
                for (int off = 8; off; off >>= 1) {
                    sum += __shfl_xor(sum, off, 16);
                    bp  += __shfl_xor(bp,  off, 16);
                }
                if (tid == 0) {
                    misc[2] = bp;
                    ck_m = m;
                    st_pair(CH2 + 2*(b*WGB + wg), sum, 0u);   // {psum, 0}
                }
            }
        }
        __syncthreads();   // SYNC_A1: wv, misc[2], hw, hrN, xws visible

        // ================= PHASE A2: pm partial publish =================
        if (doW) {
            float p = misc[2]*hw_r;
            #pragma unroll
            for (int r = 0; r < WR; ++r) p += wv[r]*mems[r*MLD + tid];
            st_coh(&PMf[((size_t)b*WGB + wg)*DD + tid], p);
        }

        // ================= PHASE A3 (drain hides under this) =================
        if (s >= 2) {    // mem_{s-3} -> mem_{s-2}
            #pragma unroll
            for (int r = 0; r < WR; ++r) {
                const float z = zp[r];
                float* mp = &mems[r*MLD + tid];
                *mp = *mp*(1.f - z) + hw_r*z;
            }
        }
        if (doW) {       // hw@Uw + o@F GEMV partial
            const int kc = tid >> 5, cl = tid & 31, k0 = kc*32;
            float a = 0.f;
            #pragma unroll 8
            for (int k = k0; k < k0+32; ++k)
                a += hw[k]*Uws[k*32+cl] + hrO_s[k]*Fs[k*32+cl];
            zredW[tid] = a;
        }
        asm volatile("s_waitcnt vmcnt(0)" ::: "memory");   // pm+CH2 retired (free)
        __syncthreads();   // SYNC_A2
        if (doW && tid == 0)
            st_pair(FLG + 2*(b*WGB + wg), ck_m, us);       // certifies pm+CH2

        // ================= PHASE B =================
        float pmx_r = 0.f, ps_r = 0.f;
        f32x4 a0={},a1={},a2={},a3={},a4={},a5={},a6={},a7={};
        const int w0 = tid >> 6, dq = tid & 63;
        if (doW) {
            // B1a: cheap FLG poll (8B), u64 tag compare
            const unsigned* pfl = FLG + 2*(b*WGB + (tid & 31));
            const unsigned long long tf = ((unsigned long long)us) << 32;
            unsigned long long flgp;
            asm volatile(
                "1:\n\t"
                "global_load_dwordx2 %[f], %[pf], off sc0 sc1\n\t"
                "s_waitcnt vmcnt(0)\n\t"
                "v_cmp_gt_u64 vcc, %[t], %[f]\n\t"
                "s_cbranch_vccnz 1b"
                : [f]"=&v"(flgp)
                : [pf]"v"(pfl), [t]"s"(tf)
                : "vcc", "memory");
            pmx_r = __uint_as_float((unsigned)flgp);
            // B1b: certified batch load: CH2 pair + 8x dwordx4 pm
            const float* pmb = PMf + (size_t)b*WGB*DD;
            const unsigned* pc2 = CH2 + 2*(b*WGB + (tid & 31));
            unsigned long long c2p;
            asm volatile(
                "global_load_dwordx2 %[c], %[pc], off sc0 sc1\n\t"
                "global_load_dwordx4 %[a0], %[q0], off sc0 sc1\n\t"
                "global_load_dwordx4 %[a1], %[q1], off sc0 sc1\n\t"
                "global_load_dwordx4 %[a2], %[q2], off sc0 sc1\n\t"
                "global_load_dwordx4 %[a3], %[q3], off sc0 sc1\n\t"
                "global_load_dwordx4 %[a4], %[q4], off sc0 sc1\n\t"
                "global_load_dwordx4 %[a5], %[q5], off sc0 sc1\n\t"
                "global_load_dwordx4 %[a6], %[q6], off sc0 sc1\n\t"
                "global_load_dwordx4 %[a7], %[q7], off sc0 sc1\n\t"
                "s_waitcnt vmcnt(0)"
                : [c]"=&v"(c2p),
                  [a0]"=&v"(a0), [a1]"=&v"(a1), [a2]"=&v"(a2), [a3]"=&v"(a3),
                  [a4]"=&v"(a4), [a5]"=&v"(a5), [a6]"=&v"(a6), [a7]"=&v"(a7)
                : [pc]"v"(pc2),
                  [q0]"v"((const f32x4*)(pmb + (w0+ 0)*DD) + dq),
                  [q1]"v"((const f32x4*)(pmb + (w0+ 4)*DD) + dq),
                  [q2]"v"((const f32x4*)(pmb + (w0+ 8)*DD) + dq),
                  [q3]"v"((const f32x4*)(pmb + (w0+12)*DD) + dq),
                  [q4]"v"((const f32x4*)(pmb + (w0+16)*DD) + dq),
                  [q5]"v"((const f32x4*)(pmb + (w0+20)*DD) + dq),
                  [q6]"v"((const f32x4*)(pmb + (w0+24)*DD) + dq),
                  [q7]"v"((const f32x4*)(pmb + (w0+28)*DD) + dq)
                : "memory");
            ps_r = __uint_as_float((unsigned)c2p);
        }
        if (doW && tid < 32) {   // global softmax weights
            float g = pmx_r;
            #pragma unroll
            for (int off = 16; off; off >>= 1) g = fmaxf(g, __shfl_xor(g, off, 32));
            const float fw = __expf(pmx_r - g);
            float S = ps_r*fw;
            #pragma unroll
            for (int off = 16; off; off >>= 1) S += __shfl_xor(S, off, 32);
            fwS[tid] = fw;
            if (tid == 0)  misc[1] = 1.f/S;
            if (tid == wg) misc[0] = fw/S;
        }
        __syncthreads();   // SYNC_B1: fwS, misc visible

        if (s <= LL-2) {   // reader GEMV partial
            const int kc = tid >> 5, cl = tid & 31, k0 = kc*32;
            float a = 0.f;
            #pragma unroll 8
            for (int k = k0; k < k0+32; ++k) a += hrN_s[k]*Urs[k*32+cl];
            zredR[tid] = a;
        }
        if (doW) {
            f32x4 acc = a0*fwS[w0];
            acc += a1*fwS[w0+4];  acc += a2*fwS[w0+8];
            acc += a3*fwS[w0+12]; acc += a4*fwS[w0+16];
            acc += a5*fwS[w0+20]; acc += a6*fwS[w0+24];
            acc += a7*fwS[w0+28];
            *(f32x4*)(red4 + w0*DD + dq*4) = acc;
        }
        __syncthreads();   // SYNC_B2: red4, zredR visible
        if (doW) {
            ms[tid] = (red4[tid] + red4[DD+tid] + red4[2*DD+tid] + red4[3*DD+tid]) * misc[1];
            if (tid < 16) zp[tid] = esx[tid]*misc[0];   // z_{s-1} for next step
        }
        __syncthreads();   // SYNC_B3: ms visible
        if (doW) {         // += ms@Bm  (zredW already holds hw@Uw + o@F)
            const int kc = tid >> 5, cl = tid & 31, k0 = kc*32;
            float a = zredW[tid];
            #pragma unroll 8
            for (int k = k0; k < k0+32; ++k) a += ms[k]*Bms[k*32+cl];
            zredW[tid] = a;
        }
        __syncthreads();   // SYNC_B4
        if (tid < 32) {
            if (doW) {
                float z = b2s[tid];
                #pragma unroll
                for (int q = 0; q < 8; ++q) z += zredW[q*32 + tid];
                zws[tid] = z;
            }
            if (s <= LL-2) {
                float z = xws[tid];
                #pragma unroll
                for (int q = 0; q < 8; ++q) z += zredR[q*32 + tid];
                zrs[tid] = z;
            }
        }
        __syncthreads();   // SYNC_B5: zws, zrs visible

        if (doW && tid < 8) {   // writer gates: publish tagged h_w + rho
            const float ig = hsig(zws[tid]);
            const float fg = hsig(zws[8+tid]);
            const float gg = tanhf(zws[16+tid]);
            const float og = hsig(zws[24+tid]);
            const float c  = fg*cw[tid] + ig*gg;
            cw[tid] = c;
            const float h = og*tanhf(c);
            st_pair(HWT + 2*((size_t)b*DD + U0 + tid), h, us);
            if (s < LL) {
                float rr = h * hrN_s[U0 + tid];    // o_s . h_w(s-1), own slice
                rr += __shfl_down(rr, 4, 8);
                rr += __shfl_down(rr, 2, 8);
                rr += __shfl_down(rr, 1, 8);
                if (tid == 0) st_pair(RHOT + 2*(b*WGB + wg), rr, us);
            }
            if (s == LL) out[b*DD + U0 + tid] = h;
        }
        if (s <= LL-2 && tid < 8) {   // reader gates: publish tagged h_r[s+1]
            const float ig = hsig(zrs[tid]);
            const float fg = hsig(zrs[8+tid]);
            const float gg = tanhf(zrs[16+tid]);
            const float og = hsig(zrs[24+tid]);
            const float c  = fg*cr[tid] + ig*gg;
            cr[tid] = c;
            st_pair(HRT + 2*((((size_t)((s+1)&1))*BB + b)*DD + U0 + tid),
                    og*tanhf(c), us + 1u);
        }
        // d1' = h_r[s] . mem_{s-2} rows (WG-local, next step's scores)
        if (s < LL) {
            const int r = tid >> 4, j = tid & 15;
            float a = 0.f;
            const float* mrow = mems + r*MLD;
            #pragma unroll 4
            for (int d = j; d < DD; d += 16) a += hrN_s[d]*mrow[d];
            #pragma unroll
            for (int off = 8; off; off >>= 1) a += __shfl_down(a, off, 16);
            if (j == 0) d1[r] = a;
        }
        __syncthreads();   // SYNC_END: d1/wv/mems stable before next A1
    }
}

extern "C" void kernel_launch(void* const* d_in, const int* in_sizes, int n_in,
                              void* d_out, int out_size, void* d_ws, size_t ws_size,
                              hipStream_t stream) {
    const float* x   = (const float*)d_in[0];
    const float* W_r = (const float*)d_in[1];
    const float* U_r = (const float*)d_in[2];
    const float* b_r = (const float*)d_in[3];
    const float* W_w = (const float*)d_in[4];
    const float* U_w = (const float*)d_in[5];
    const float* b_w = (const float*)d_in[6];
    const float* W_c = (const float*)d_in[7];
    const float* b_c = (const float*)d_in[8];
    (void)in_sizes; (void)n_in;

    if (ws_size < TOTAL_WS * sizeof(float)) return;

    float* ws   = (float*)d_ws;
    float* XW   = ws + OFF_XW;
    float* Fmat = ws + OFF_F;
    float* Bmw  = ws + OFF_BMW;
    float* B2   = ws + OFF_B2;
    unsigned* HRT  = (unsigned*)(ws + OFF_HRT);
    unsigned* HWT  = (unsigned*)(ws + OFF_HWT);
    unsigned* RHOT = (unsigned*)(ws + OFF_RHOT);
    unsigned* CH2  = (unsigned*)(ws + OFF_CH2);
    unsigned* FLG  = (unsigned*)(ws + OFF_FLG);
    float* PMf  = ws + OFF_PM;

    const int FUSED_LDS = 39800 * 4;   // 159200 B
    hipFuncSetAttribute((const void*)fused_kernel, hipFuncAttributeMaxDynamicSharedMemorySize, FUSED_LDS);

    // zero all tag-carrying buffers (HRT..FLG contiguous) — must restart < 1
    hipMemsetAsync(HRT, 0, (OFF_PM - OFF_HRT)*sizeof(float), stream);

    dim3 blk(256);
    // XW = x @ W_r + b_r        (4096 x 1024, K=256)
    gemm_nn<64,64,16><<<dim3(NG4/64, (BB*LL)/64), blk, 0, stream>>>(
        x, DD, W_r, NG4, b_r, XW, NG4, BB*LL, NG4, DD);
    // F  = W_c[:256,:] @ W_w    (256 x 1024, K=256)
    gemm_nn<64,64,16><<<dim3(NG4/64, DD/64), blk, 0, stream>>>(
        W_c, DD, W_w, NG4, nullptr, Fmat, NG4, DD, NG4, DD);
    // Bm = W_c[256:,:] @ W_w    (256 x 1024, K=256)
    gemm_nn<64,64,16><<<dim3(NG4/64, DD/64), blk, 0, stream>>>(
        W_c + (size_t)DD*DD, DD, W_w, NG4, nullptr, Bmw, NG4, DD, NG4, DD);
    // b2 = b_c @ W_w + b_w
    b2_kernel<<<dim3(NG4/256), blk, 0, stream>>>(b_c, W_w, b_w, B2);
    // fused persistent reader+writer
    fused_kernel<<<dim3(BB*WGB), blk, FUSED_LDS, stream>>>(
        XW, Fmat, Bmw, B2, U_r, U_w, x, HRT, HWT, RHOT, CH2, FLG, PMf, (float*)d_out);
}

// Round 12
// 3790.322 us; speedup vs baseline: 1.1470x; 1.1470x over previous
//
#include <hip/hip_runtime.h>
#include <math.h>

#define BB 8
#define LL 512
#define DD 256
#define NG4 1024
#define WGB 32     // WGs per batch
#define WR 16      // mem rows per WG
#define WU 8       // units per WG
#define MLD 264    // padded leading dim for mems tile

typedef __attribute__((ext_vector_type(4))) float f32x4;
typedef __attribute__((ext_vector_type(2))) unsigned u32x2;
typedef __attribute__((ext_vector_type(4))) unsigned u32x4;

// ---- workspace layout (float offsets) ----
static const size_t OFF_XW    = 0;
static const size_t OFF_F     = OFF_XW + (size_t)BB*LL*NG4;     // F = Wc_top @ Ww   (256x1024)
static const size_t OFF_BMW   = OFF_F + (size_t)DD*NG4;         // Bm = Wc_bot @ Ww  (256x1024)
static const size_t OFF_B2    = OFF_BMW + (size_t)DD*NG4;       // b2 = b_c@Ww + b_w (1024)
static const size_t OFF_HRT   = OFF_B2 + NG4;                   // [2][B][256] {val,tag}
static const size_t OFF_HWT   = OFF_HRT + (size_t)2*BB*DD*2;    // [B][256] pairs
static const size_t OFF_RHOT  = OFF_HWT + (size_t)BB*DD*2;      // [B][32] pairs
static const size_t OFF_CHUNK = OFF_RHOT + (size_t)BB*WGB*2;    // [B][32] {pmax,psum,tag,0}
static const size_t OFF_PM    = OFF_CHUNK + (size_t)BB*WGB*4;   // [B][32][256] plain
static const size_t TOTAL_WS  = OFF_PM + (size_t)BB*WGB*DD;     // floats

__device__ __forceinline__ float hsig(float x) {
    return fminf(fmaxf(0.2f*x + 0.5f, 0.0f), 1.0f);
}

// coherent (MALL, sc0 sc1) primitives — the validated cross-XCD path
__device__ __forceinline__ void st_coh(float* p, float v) {
    __hip_atomic_store(p, v, __ATOMIC_RELAXED, __HIP_MEMORY_SCOPE_AGENT);
}
// tagged 8B pair: {f32 value, u32 epoch} in ONE instruction
__device__ __forceinline__ void st_pair(unsigned* p, float v, unsigned tag) {
    u32x2 d; d[0] = __float_as_uint(v); d[1] = tag;
    asm volatile("global_store_dwordx2 %0, %1, off sc0 sc1" :: "v"(p), "v"(d) : "memory");
}
__device__ __forceinline__ u32x2 ld_pair(const unsigned* p) {
    u32x2 r;
    asm volatile("global_load_dwordx2 %0, %1, off sc0 sc1\n\ts_waitcnt vmcnt(0)"
                 : "=&v"(r) : "v"(p) : "memory");
    return r;
}
__device__ __forceinline__ float poll_pair(const unsigned* p, unsigned tag) {
    for (;;) {
        u32x2 r = ld_pair(p);
        if (r[1] >= tag) return __uint_as_float(r[0]);
    }
}
__device__ __forceinline__ u32x4 ld_chunk(const unsigned* p) {
    u32x4 r;
    asm volatile("global_load_dwordx4 %0, %1, off sc0 sc1\n\ts_waitcnt vmcnt(0)"
                 : "=&v"(r) : "v"(p) : "memory");
    return r;
}
// 8 coherent float4 loads, single drain (pipelined at MALL)
__device__ __forceinline__ void ld_pm8(
    const f32x4* p0, const f32x4* p1, const f32x4* p2, const f32x4* p3,
    const f32x4* p4, const f32x4* p5, const f32x4* p6, const f32x4* p7,
    f32x4& a0, f32x4& a1, f32x4& a2, f32x4& a3,
    f32x4& a4, f32x4& a5, f32x4& a6, f32x4& a7)
{
    asm volatile(
        "global_load_dwordx4 %0, %8, off sc0 sc1\n\t"
        "global_load_dwordx4 %1, %9, off sc0 sc1\n\t"
        "global_load_dwordx4 %2, %10, off sc0 sc1\n\t"
        "global_load_dwordx4 %3, %11, off sc0 sc1\n\t"
        "global_load_dwordx4 %4, %12, off sc0 sc1\n\t"
        "global_load_dwordx4 %5, %13, off sc0 sc1\n\t"
        "global_load_dwordx4 %6, %14, off sc0 sc1\n\t"
        "global_load_dwordx4 %7, %15, off sc0 sc1\n\t"
        "s_waitcnt vmcnt(0)"
        : "=&v"(a0), "=&v"(a1), "=&v"(a2), "=&v"(a3),
          "=&v"(a4), "=&v"(a5), "=&v"(a6), "=&v"(a7)
        : "v"(p0), "v"(p1), "v"(p2), "v"(p3),
          "v"(p4), "v"(p5), "v"(p6), "v"(p7)
        : "memory");
}

// ---- simple fp32 tiled GEMM ----
template<int TM, int TN, int TK>
__global__ void __launch_bounds__(256) gemm_nn(
    const float* __restrict__ A, int lda,
    const float* __restrict__ Bmat, int ldb,
    const float* __restrict__ bias,
    float* __restrict__ C, int ldc,
    int M, int N, int K)
{
    __shared__ float As[TK][TM];
    __shared__ float Bs[TK][TN];
    const int m0 = blockIdx.y * TM, n0 = blockIdx.x * TN;
    const int tid = threadIdx.x;
    const int tx = tid % (TN/4);
    const int ty = tid / (TN/4);
    float acc[4][4] = {};
    for (int k0 = 0; k0 < K; k0 += TK) {
        {
            const int e = tid*4;
            const int m = e / TK, k = e % TK;
            const float4 v = *reinterpret_cast<const float4*>(&A[(size_t)(m0+m)*lda + k0 + k]);
            As[k+0][m] = v.x; As[k+1][m] = v.y; As[k+2][m] = v.z; As[k+3][m] = v.w;
        }
        {
            const int e = tid*4;
            const int k = e / TN, n = e % TN;
            const float4 v = *reinterpret_cast<const float4*>(&Bmat[(size_t)(k0+k)*ldb + n0 + n]);
            Bs[k][n+0] = v.x; Bs[k][n+1] = v.y; Bs[k][n+2] = v.z; Bs[k][n+3] = v.w;
        }
        __syncthreads();
        #pragma unroll
        for (int kk = 0; kk < TK; ++kk) {
            float a[4], bv[4];
            #pragma unroll
            for (int i = 0; i < 4; ++i) a[i] = As[kk][ty*4+i];
            #pragma unroll
            for (int j = 0; j < 4; ++j) bv[j] = Bs[kk][tx*4+j];
            #pragma unroll
            for (int i = 0; i < 4; ++i)
                #pragma unroll
                for (int j = 0; j < 4; ++j) acc[i][j] += a[i]*bv[j];
        }
        __syncthreads();
    }
    #pragma unroll
    for (int i = 0; i < 4; ++i) {
        const int m = m0 + ty*4 + i;
        #pragma unroll
        for (int j = 0; j < 4; ++j) {
            const int n = n0 + tx*4 + j;
            C[(size_t)m*ldc + n] = acc[i][j] + (bias ? bias[n] : 0.0f);
        }
    }
}

// b2[n] = b_w[n] + sum_k b_c[k]*W_w[k][n]
__global__ void __launch_bounds__(256) b2_kernel(
    const float* __restrict__ bc, const float* __restrict__ Ww,
    const float* __restrict__ bw, float* __restrict__ B2)
{
    const int n = blockIdx.x*256 + threadIdx.x;
    float a = bw[n];
    for (int k = 0; k < DD; ++k) a += bc[k]*Ww[(size_t)k*NG4 + n];
    B2[n] = a;
}

// ---- fused reader+writer persistent kernel, barrier-free (r8 protocol) ----
// Identical dataflow/protocol to the validated round-8 kernel. ONE change:
// the mem-update + zredW GEMV (WG-local, exchange-free) now run BETWEEN the
// pm stores and their vmcnt(0) drain, so the drain retires under compute.
// Safety: pm reads and mem-update writes of `mems` are thread-column-
// exclusive (thread t touches only column t) -> thread-local order suffices.
__global__ void __launch_bounds__(256) fused_kernel(
    const float* __restrict__ XW, const float* __restrict__ Fw,
    const float* __restrict__ Bm, const float* __restrict__ B2,
    const float* __restrict__ Ur, const float* __restrict__ Uw,
    const float* __restrict__ x,
    unsigned* __restrict__ HRT, unsigned* __restrict__ HWT,
    unsigned* __restrict__ RHOT, unsigned* __restrict__ CHUNK,
    float* __restrict__ PM, float* __restrict__ out)
{
    extern __shared__ float sm[];
    float* Urs  = sm;              // [256][32]
    float* Uws  = Urs + 8192;      // [256][32]
    float* Fs   = Uws + 8192;      // [256][32]
    float* Bms  = Fs + 8192;       // [256][32]
    float* mems = Bms + 8192;      // [16][MLD]
    float* hr2  = mems + WR*MLD;   // [2][256] h_r parity slots
    float* hw   = hr2 + 512;       // 256
    float* ms   = hw + 256;        // 256
    float* zredR= ms + 256;        // 256
    float* zredW= zredR + 256;     // 256
    float* red4 = zredW + 256;     // [4][256]
    float* xws  = red4 + 1024;     // 32
    float* b2s  = xws + 32;        // 32
    float* zrs  = b2s + 32;        // 32
    float* zws  = zrs + 32;        // 32
    float* fwS  = zws + 32;        // 32
    float* d1   = fwS + 32;        // 16
    float* zp   = d1 + 16;         // 16
    float* esx  = zp + 16;         // 16
    float* wv   = esx + 16;        // 16
    float* cr   = wv + 16;         // 8
    float* cw   = cr + 8;          // 8
    float* misc = cw + 8;          // [0]=scale, [1]=invS, [2]=beta

    const int b   = (int)blockIdx.x & 7;
    const int wg  = (int)blockIdx.x >> 3;   // 0..31
    const int tid = threadIdx.x;
    const int R0  = wg*WR;
    const int U0  = wg*WU;
    const int gc32 = (tid>>3)*DD + U0 + (tid&7);   // global col for lane<32

    // --- init: weight slices ---
    for (int it = 0; it < 32; ++it) {
        const int e = it*256 + tid;
        const int k = e >> 5, cl = e & 31;
        const int gc = (cl>>3)*DD + U0 + (cl&7);
        Urs[k*32+cl] = Ur[(size_t)k*NG4 + gc];
        Uws[k*32+cl] = Uw[(size_t)k*NG4 + gc];
        Fs [k*32+cl] = Fw[(size_t)k*NG4 + gc];
        Bms[k*32+cl] = Bm[(size_t)k*NG4 + gc];
    }
    if (tid < 32) b2s[tid] = B2[gc32];
    for (int r = 0; r < WR; ++r)
        mems[r*MLD + tid] = x[((size_t)b*LL + R0 + r)*DD + tid];
    // prologue: full h_r[0] computed locally (h=0 -> z = XW row 0)
    {
        const size_t base = (size_t)b*LL*NG4;
        const float zi = XW[base + tid];
        const float zg = XW[base + 512 + tid];
        const float zo = XW[base + 768 + tid];
        const float c0 = hsig(zi)*tanhf(zg);
        hr2[tid] = hsig(zo)*tanhf(c0);
        hr2[256 + tid] = 0.f;
        if (tid >= U0 && tid < U0+WU) cr[tid-U0] = c0;
    }
    if (tid < 16) { zp[tid] = 0.f; d1[tid] = 0.f; esx[tid] = 0.f; }
    if (tid < 8)  cw[tid] = 0.f;
    if (tid < 4)  misc[tid] = 0.f;
    __syncthreads();

    for (int s = 0; s <= LL; ++s) {
        const bool doW = (s >= 1);
        const unsigned us = (unsigned)s;
        float* hrN_s = hr2 + (s&1)*256;        // h_r[s]
        float* hrO_s = hr2 + ((s+1)&1)*256;    // h_r[s-1] = o_tau

        // ================= PHASE A =================
        if (s <= LL-2 && tid < 32)
            xws[tid] = XW[((size_t)b*LL + s + 1)*NG4 + gc32];   // wave0-local prefetch

        float hw_r = 0.f, rho_r = 0.f;
        if (s >= 2) {
            hw_r = poll_pair(HWT + 2*((size_t)b*DD + tid), us - 1u);   // h_w(s-2)
            if (tid < 32)
                rho_r = poll_pair(RHOT + 2*(b*WGB + tid), us - 1u);    // o_{s-1}.h_w(s-2) slices
        }
        hw[tid] = hw_r;
        __syncthreads();   // SYNC_A0: hw visible; prev-step LDS (d1,zp,esx) stable

        // d2 from rho partials + local softmax (wave 0 only)
        float ck_m = 0.f, ck_s = 0.f;
        if (tid < 32) {
            float d2 = rho_r;
            #pragma unroll
            for (int off = 16; off; off >>= 1) d2 += __shfl_xor(d2, off, 32);
            if (doW && tid < 16) {
                const float zpv = zp[tid];
                const float sc  = (1.f - zpv)*d1[tid] + zpv*d2;
                float m = sc;
                #pragma unroll
                for (int off = 8; off; off >>= 1) m = fmaxf(m, __shfl_xor(m, off, 16));
                const float e = __expf(sc - m);
                esx[tid] = e;
                wv[tid]  = e*(1.f - zpv);
                float sum = e, bp = e*zpv;
                #pragma unroll
                for (int off = 8; off; off >>= 1) {
                    sum += __shfl_xor(sum, off, 16);
                    bp  += __shfl_xor(bp,  off, 16);
                }
                if (tid == 0) { misc[2] = bp; ck_m = m; ck_s = sum; }
            }
        }
        __syncthreads();   // SYNC_A1: wv, misc[2] visible

        if (doW) {   // pm partial over mem_{s-2} via decomposition (mems = mem_{s-3})
            float p = misc[2]*hw_r;
            #pragma unroll
            for (int r = 0; r < WR; ++r) p += wv[r]*mems[r*MLD + tid];
            st_coh(&PM[((size_t)b*WGB + wg)*DD + tid], p);
        }

        // --- WG-local work moved here: drain retires underneath it ---
        if (s >= 2) {    // mem_{s-3} -> mem_{s-2} (thread-column exclusive)
            #pragma unroll
            for (int r = 0; r < WR; ++r) {
                const float z = zp[r];
                float* mp = &mems[r*MLD + tid];
                *mp = *mp*(1.f - z) + hw_r*z;
            }
        }
        if (doW) {       // hw@Uw + o@F GEMV partial
            const int kc = tid >> 5, cl = tid & 31, k0 = kc*32;
            float a = 0.f;
            #pragma unroll 8
            for (int k = k0; k < k0+32; ++k)
                a += hw[k]*Uws[k*32+cl] + hrO_s[k]*Fs[k*32+cl];
            zredW[tid] = a;
        }

        // drain pm stores (nearly free now), then publish tagged chunk
        asm volatile("s_waitcnt vmcnt(0)" ::: "memory");
        __syncthreads();   // SYNC_A2: whole WG's pm acked at MALL
        if (doW && tid == 0) {
            u32x4 d; d[0] = __float_as_uint(ck_m); d[1] = __float_as_uint(ck_s);
            d[2] = us; d[3] = 0u;
            unsigned* cp = CHUNK + 4*(b*WGB + wg);
            asm volatile("global_store_dwordx4 %0, %1, off sc0 sc1" :: "v"(cp), "v"(d) : "memory");
        }

        // ================= PHASE B =================
        float hrN_r = 0.f;
        if (s >= 1 && s <= LL-1)
            hrN_r = poll_pair(HRT + 2*(((size_t)(s&1)*BB + b)*DD + tid), us);
        float pmx_r = 0.f, ps_r = 0.f;
        if (doW && tid < 32) {
            const unsigned* cp = CHUNK + 4*(b*WGB + tid);
            u32x4 ck;
            do { ck = ld_chunk(cp); } while (ck[2] < us);
            pmx_r = __uint_as_float(ck[0]); ps_r = __uint_as_float(ck[1]);
        }
        if (s >= 1 && s <= LL-1) hrN_s[tid] = hrN_r;
        __syncthreads();   // SYNC_B1: hrN visible; wave0 confirmed all chunks@s

        f32x4 a0={},a1={},a2={},a3={},a4={},a5={},a6={},a7={};
        const int w0 = tid >> 6, dq = tid & 63;
        if (doW) {
            const float* pmb = PM + (size_t)b*WGB*DD;
            ld_pm8((const f32x4*)(pmb + (w0+ 0)*DD) + dq, (const f32x4*)(pmb + (w0+ 4)*DD) + dq,
                   (const f32x4*)(pmb + (w0+ 8)*DD) + dq, (const f32x4*)(pmb + (w0+12)*DD) + dq,
                   (const f32x4*)(pmb + (w0+16)*DD) + dq, (const f32x4*)(pmb + (w0+20)*DD) + dq,
                   (const f32x4*)(pmb + (w0+24)*DD) + dq, (const f32x4*)(pmb + (w0+28)*DD) + dq,
                   a0,a1,a2,a3,a4,a5,a6,a7);
        }
        if (doW && tid < 32) {   // global softmax weights
            float g = pmx_r;
            #pragma unroll
            for (int off = 16; off; off >>= 1) g = fmaxf(g, __shfl_xor(g, off, 32));
            const float fw = __expf(pmx_r - g);
            float S = ps_r*fw;
            #pragma unroll
            for (int off = 16; off; off >>= 1) S += __shfl_xor(S, off, 32);
            fwS[tid] = fw;
            if (tid == 0)  misc[1] = 1.f/S;
            if (tid == wg) misc[0] = fw/S;
        }
        if (s <= LL-2) {   // reader GEMV partial
            const int kc = tid >> 5, cl = tid & 31, k0 = kc*32;
            float a = 0.f;
            #pragma unroll 8
            for (int k = k0; k < k0+32; ++k) a += hrN_s[k]*Urs[k*32+cl];
            zredR[tid] = a;
        }
        __syncthreads();   // SYNC_B2: fwS, misc, zredR visible

        if (doW) {
            f32x4 acc = a0*fwS[w0];
            acc += a1*fwS[w0+4];  acc += a2*fwS[w0+8];
            acc += a3*fwS[w0+12]; acc += a4*fwS[w0+16];
            acc += a5*fwS[w0+20]; acc += a6*fwS[w0+24];
            acc += a7*fwS[w0+28];
            *(f32x4*)(red4 + w0*DD + dq*4) = acc;
        }
        __syncthreads();   // SYNC_B3: red4 visible
        if (doW) {
            ms[tid] = (red4[tid] + red4[DD+tid] + red4[2*DD+tid] + red4[3*DD+tid]) * misc[1];
            if (tid < 16) zp[tid] = esx[tid]*misc[0];   // z_{s-1} for next step
        }
        __syncthreads();   // SYNC_B4: ms visible
        if (doW) {         // += ms@Bm  (zredW already holds hw@Uw + o@F)
            const int kc = tid >> 5, cl = tid & 31, k0 = kc*32;
            float a = zredW[tid];
            #pragma unroll 8
            for (int k = k0; k < k0+32; ++k) a += ms[k]*Bms[k*32+cl];
            zredW[tid] = a;
        }
        __syncthreads();   // SYNC_B5
        if (tid < 32) {
            if (doW) {
                float z = b2s[tid];
                #pragma unroll
                for (int q = 0; q < 8; ++q) z += zredW[q*32 + tid];
                zws[tid] = z;
            }
            if (s <= LL-2) {
                float z = xws[tid];
                #pragma unroll
                for (int q = 0; q < 8; ++q) z += zredR[q*32 + tid];
                zrs[tid] = z;
            }
        }
        __syncthreads();   // SYNC_B6: zws, zrs visible

        if (doW && tid < 8) {   // writer gates: publish tagged h_w slice + rho
            const float ig = hsig(zws[tid]);
            const float fg = hsig(zws[8+tid]);
            const float gg = tanhf(zws[16+tid]);
            const float og = hsig(zws[24+tid]);
            const float c  = fg*cw[tid] + ig*gg;
            cw[tid] = c;
            const float h = og*tanhf(c);
            st_pair(HWT + 2*((size_t)b*DD + U0 + tid), h, us);
            if (s < LL) {
                float rr = h * hrN_s[U0 + tid];    // o_s . h_w(s-1), own slice
                rr += __shfl_down(rr, 4, 8);
                rr += __shfl_down(rr, 2, 8);
                rr += __shfl_down(rr, 1, 8);
                if (tid == 0) st_pair(RHOT + 2*(b*WGB + wg), rr, us);
            }
            if (s == LL) out[b*DD + U0 + tid] = h;
        }
        if (s <= LL-2 && tid < 8) {   // reader gates: publish tagged h_r[s+1] slice
            const float ig = hsig(zrs[tid]);
            const float fg = hsig(zrs[8+tid]);
            const float gg = tanhf(zrs[16+tid]);
            const float og = hsig(zrs[24+tid]);
            const float c  = fg*cr[tid] + ig*gg;
            cr[tid] = c;
            st_pair(HRT + 2*(((size_t)((s+1)&1)*BB + b)*DD + U0 + tid),
                    og*tanhf(c), us + 1u);
        }
        // d1' = h_r[s] . mem_{s-2} rows (WG-local, for next step's scores)
        if (s < LL) {
            const int r = tid >> 4, j = tid & 15;
            float a = 0.f;
            const float* mrow = mems + r*MLD;
            #pragma unroll 4
            for (int d = j; d < DD; d += 16) a += hrN_s[d]*mrow[d];
            #pragma unroll
            for (int off = 8; off; off >>= 1) a += __shfl_down(a, off, 16);
            if (j == 0) d1[r] = a;
        }
        // no trailing barrier — next step's polls self-synchronize
    }
}

extern "C" void kernel_launch(void* const* d_in, const int* in_sizes, int n_in,
                              void* d_out, int out_size, void* d_ws, size_t ws_size,
                              hipStream_t stream) {
    const float* x   = (const float*)d_in[0];
    const float* W_r = (const float*)d_in[1];
    const float* U_r = (const float*)d_in[2];
    const float* b_r = (const float*)d_in[3];
    const float* W_w = (const float*)d_in[4];
    const float* U_w = (const float*)d_in[5];
    const float* b_w = (const float*)d_in[6];
    const float* W_c = (const float*)d_in[7];
    const float* b_c = (const float*)d_in[8];
    (void)in_sizes; (void)n_in;

    if (ws_size < TOTAL_WS * sizeof(float)) return;

    float* ws   = (float*)d_ws;
    float* XW   = ws + OFF_XW;
    float* Fmat = ws + OFF_F;
    float* Bmw  = ws + OFF_BMW;
    float* B2   = ws + OFF_B2;
    unsigned* HRT   = (unsigned*)(ws + OFF_HRT);
    unsigned* HWT   = (unsigned*)(ws + OFF_HWT);
    unsigned* RHOT  = (unsigned*)(ws + OFF_RHOT);
    unsigned* CHUNK = (unsigned*)(ws + OFF_CHUNK);
    float* PM   = ws + OFF_PM;

    const int FUSED_LDS = 39800 * 4;   // 159200 B
    hipFuncSetAttribute((const void*)fused_kernel, hipFuncAttributeMaxDynamicSharedMemorySize, FUSED_LDS);

    // zero all tag-carrying buffers (HRT..CHUNK contiguous)
    hipMemsetAsync(HRT, 0, (OFF_PM - OFF_HRT)*sizeof(float), stream);

    dim3 blk(256);
    // XW = x @ W_r + b_r        (4096 x 1024, K=256)
    gemm_nn<64,64,16><<<dim3(NG4/64, (BB*LL)/64), blk, 0, stream>>>(
        x, DD, W_r, NG4, b_r, XW, NG4, BB*LL, NG4, DD);
    // F  = W_c[:256,:] @ W_w    (256 x 1024, K=256)
    gemm_nn<64,64,16><<<dim3(NG4/64, DD/64), blk, 0, stream>>>(
        W_c, DD, W_w, NG4, nullptr, Fmat, NG4, DD, NG4, DD);
    // Bm = W_c[256:,:] @ W_w    (256 x 1024, K=256)
    gemm_nn<64,64,16><<<dim3(NG4/64, DD/64), blk, 0, stream>>>(
        W_c + (size_t)DD*DD, DD, W_w, NG4, nullptr, Bmw, NG4, DD, NG4, DD);
    // b2 = b_c @ W_w + b_w
    b2_kernel<<<dim3(NG4/256), blk, 0, stream>>>(b_c, W_w, b_w, B2);
    // fused persistent reader+writer (barrier-free, tagged-data sync)
    fused_kernel<<<dim3(BB*WGB), blk, FUSED_LDS, stream>>>(
        XW, Fmat, Bmw, B2, U_r, U_w, x, HRT, HWT, RHOT, CHUNK, PM, (float*)d_out);
}